// Round 9
// baseline (226.129 us; speedup 1.0000x reference)
//
#include <hip/hip_runtime.h>
#include <math.h>

#define B_   16
#define O_   1024
#define M_   64
#define C_   32
#define INO  16
#define INA  8
#define SLOPE 0.2f

// per-block partials: 50 fields x 64 m-lanes (r0-style field layout:
// [0]=l_in, [1..8]=ai, [9..24]=aoi, [25]=l_out, [26..41]=aoo, [42..49]=sao)
#define NPQ   3200
#define NSG   32             // o groups of 32 rows
#define GRID  (2*B_*NSG)     // 1024 blocks

// workspace layout (float offsets)
#define WS_EOPE   0
#define WS_ENODE  (WS_EOPE + B_*O_)              // 16384
#define WS_PNODE  (WS_ENODE + 2*B_*M_)           // 18432
#define WS_WARC   (WS_PNODE + 2*B_*M_*C_)        // 83968
#define WS_MASK   (WS_WARC + 16)                 // 83984 (8192 floats = 32 KB packed adj bits)
#define WS_PART   (WS_MASK + 8192)               // 92176 (GRID*NPQ floats = 13.1 MB; ws is 256 MiB)

typedef float f32x4 __attribute__((ext_vector_type(4)));

__device__ inline float rfl(float x) {
    return __int_as_float(__builtin_amdgcn_readfirstlane(__float_as_int(x)));
}

// non-temporal (no-allocate) 16B load. r6: first lever that moved k_main
// (52 -> ~38us, bypassing the 2.7 TB/s MALL-mixed path). r7/r8: NT path
// plateaus ~3.5 TB/s -- exactly HALF the 6.3 TB/s stream rate, matching the
// h-split theory (every 2KB DRAM row activated twice for 1KB each).
__device__ __forceinline__ f32x4 ntload4(const float* p) {
    return __builtin_nontemporal_load((const f32x4*)p);
}
__device__ __forceinline__ void ntstore(float* p, float v) {
    __builtin_nontemporal_store(v, p);
}

// ---------------- kernel 0: precompute (unchanged from r8) ----------------
__global__ void k_pre(const float* __restrict__ adj0, const float* __restrict__ adj1,
                      const float* __restrict__ adj2, const float* __restrict__ adj3,
                      const float* __restrict__ feat_opes,
                      const float* __restrict__ feat_mas,
                      const float* __restrict__ feat_buf,
                      const float* __restrict__ W_ope,
                      const float* __restrict__ W_mas,
                      const float* __restrict__ W_buf,
                      const float* __restrict__ W_arc_in,
                      const float* __restrict__ W_arc_out,
                      const float* __restrict__ attn_ope,
                      const float* __restrict__ attn_mas,
                      const float* __restrict__ attn_arc,
                      float* __restrict__ ws) {
    int tid = threadIdx.x;
    int bid = blockIdx.x;
    if (bid < 64) {
        // e_ope[b,o] = feat_opes[b,o,:] . (W_ope @ attn_ope)
        __shared__ float wo[INO];
        if (tid < INO) {
            float s = 0.f;
            for (int c = 0; c < C_; ++c) s += W_ope[tid*C_ + c]*attn_ope[c];
            wo[tid] = s;
        }
        __syncthreads();
        int idx = bid*256 + tid;                 // [0, 16384)
        const float* f = feat_opes + idx*INO;
        float s = 0.f;
#pragma unroll
        for (int j = 0; j < INO; ++j) s += f[j]*wo[j];
        ws[WS_EOPE + idx] = s;
    } else if (bid < 72) {
        // p_node / e_node for both branches
        int idx = (bid - 64)*256 + tid;          // [0, 2048)
        int br  = idx >> 10;
        int rem = idx & 1023;
        const float* f = (br == 0 ? feat_mas : feat_buf) + rem*INA;
        const float* W = (br == 0 ? W_mas : W_buf);
        float f8[INA];
#pragma unroll
        for (int k = 0; k < INA; ++k) f8[k] = f[k];
        float e = 0.f;
        float* pn = ws + WS_PNODE + idx*C_;
        for (int c = 0; c < C_; ++c) {
            float s = 0.f;
#pragma unroll
            for (int k = 0; k < INA; ++k) s += f8[k]*W[k*C_ + c];
            pn[c] = s;
            e += s*attn_mas[c];
        }
        ws[WS_ENODE + idx] = e;
    } else if (bid == 72) {
        // w_arc_in/out 8-vectors: W_arc @ attn_arc
        if (tid < 16) {
            const float* W = (tid < 8) ? W_arc_in : W_arc_out;
            int k = tid & 7;
            float s = 0.f;
            for (int c = 0; c < C_; ++c) s += W[k*C_ + c]*attn_arc[c];
            ws[WS_WARC + tid] = s;
        }
    } else {
        // bid 73..76: coalesced mask packing, one block per adjacency matrix.
        int q  = bid - 73;                  // 0:adj0(in,br0) 1:adj1(out,br0) 2:adj2 3:adj3
        const float* A = (q == 0) ? adj0 : (q == 1) ? adj1 : (q == 2) ? adj2 : adj3;
        int br = q >> 1;
        int l  = tid & 63;
        int y  = tid >> 6;
        int mq = l & 15;
        int oo = l >> 4;
        unsigned* mp = (unsigned*)(ws + WS_MASK);
        for (int t = 0; t < 8; ++t) {
            int j4 = y*8 + t;               // o-group [j4*32, j4*32+32)
            unsigned mk0 = 0u, mk1 = 0u, mk2 = 0u, mk3 = 0u;
#pragma unroll
            for (int g2 = 0; g2 < 8; ++g2) {
                int o = j4*32 + g2*4 + oo;
                float4 v = *(const float4*)(A + o*M_ + mq*4);
                unsigned bit = 1u << (g2*4 + oo);
                if (v.x == 1.0f) mk0 |= bit;
                if (v.y == 1.0f) mk1 |= bit;
                if (v.z == 1.0f) mk2 |= bit;
                if (v.w == 1.0f) mk3 |= bit;
            }
            mk0 |= (unsigned)__shfl_xor((int)mk0, 16); mk0 |= (unsigned)__shfl_xor((int)mk0, 32);
            mk1 |= (unsigned)__shfl_xor((int)mk1, 16); mk1 |= (unsigned)__shfl_xor((int)mk1, 32);
            mk2 |= (unsigned)__shfl_xor((int)mk2, 16); mk2 |= (unsigned)__shfl_xor((int)mk2, 32);
            mk3 |= (unsigned)__shfl_xor((int)mk3, 16); mk3 |= (unsigned)__shfl_xor((int)mk3, 32);
            if (oo == 0) {
                int base = (br*M_ + mq*4)*64 + (q & 1)*32 + j4;
                mp[base]        = mk0;
                mp[base + 64]   = mk1;
                mp[base + 128]  = mk2;
                mp[base + 192]  = mk3;
            }
        }
    }
}

// ---------------- kernel A: main streaming pass (full-row waves, all NT) ----------------
// r8 post-mortem: every round so far read 1KB half-rows at 2KB stride
// (h-split) -> each DRAM page activated twice for half its data; both
// measured plateaus (cached 2.7, NT 3.5 TB/s) sit at ~1/2 of their path's
// streaming rate. This round: lane = m, each wave reads the COMPLETE 2KB row
// with back-to-back NT dwordx4 -- every page touched once, in full, in order.
// Also deletes the parity split (in-lane k-dot, no shfl_xor) and folds the
// feat_opes pass into the main loop (cached broadcast; no vmcnt constraint).
__global__ __launch_bounds__(256) void k_main(
        const float* __restrict__ feat_opes,
        const float* __restrict__ fin_ma,  const float* __restrict__ fin_buf,
        const float* __restrict__ fout_ma, const float* __restrict__ fout_buf,
        float* __restrict__ ws) {
    int tid = threadIdx.x;
    int l   = tid & 63;                               // lane = m
    int y   = __builtin_amdgcn_readfirstlane(tid >> 6);

    int bid = blockIdx.x;                 // [0, 1024)
    int sg  = bid & (NSG - 1);            // 32-row group
    int b   = (bid >> 5) & (B_ - 1);
    int br  = bid >> 9;

    const float* fin  = br ? fin_buf  : fin_ma;
    const float* fout = br ? fout_buf : fout_ma;

    // cross-wave reduction area: 3 waves x 50 fields x 64 lanes = 38.4 KB
    __shared__ float smem[9600];

    float en = ws[WS_ENODE + (br*B_ + b)*M_ + l];

    // full 8-dim weight vectors, wave-uniform -> SGPRs
    const float* wv = ws + WS_WARC;
    float wi0=rfl(wv[0]), wi1=rfl(wv[1]), wi2=rfl(wv[2]), wi3=rfl(wv[3]);
    float wi4=rfl(wv[4]), wi5=rfl(wv[5]), wi6=rfl(wv[6]), wi7=rfl(wv[7]);
    float wo0=rfl(wv[8]), wo1=rfl(wv[9]), wo2=rfl(wv[10]), wo3=rfl(wv[11]);
    float wo4=rfl(wv[12]), wo5=rfl(wv[13]), wo6=rfl(wv[14]), wo7=rfl(wv[15]);

    // packed adjacency: one 32-bit word per (matrix, m) covering this block's rows
    const unsigned* mp = (const unsigned*)(ws + WS_MASK) + (br*M_ + l)*64;
    unsigned wA = mp[sg];
    unsigned wB = mp[32 + sg];
    unsigned amA = (wA >> (y*8)) & 0xffu;
    unsigned amB = (wB >> (y*8)) & 0xffu;

    int o0 = sg*32 + y*8;                 // this wave: o in [o0, o0+8)
    const float* e_ope = ws + WS_EOPE + b*O_ + o0;
    float eo[8];
#pragma unroll
    for (int i = 0; i < 8; ++i) eo[i] = rfl(e_ope[i]);

    const float* pi = fin  + (size_t)(b*O_ + o0)*512 + l*8;
    const float* po = fout + (size_t)(b*O_ + o0)*512 + l*8;
    const float* fo = feat_opes + (size_t)(b*O_ + o0)*INO;

    float ai[8], sao[8], aoi[16], aoo[16];
#pragma unroll
    for (int k = 0; k < 8; ++k)  { ai[k] = 0.f; sao[k] = 0.f; }
#pragma unroll
    for (int j = 0; j < 16; ++j) { aoi[j] = 0.f; aoo[j] = 0.f; }
    float li = 0.f, lo = 0.f;

    // depth-2 rotating NT pipeline over full rows (4 dwordx4 per row)
    f32x4 bi0[2], bi1[2], bu0[2], bu1[2];
#pragma unroll
    for (int q = 0; q < 2; ++q) {
        bi0[q] = ntload4(pi + q*512);
        bi1[q] = ntload4(pi + q*512 + 4);
        bu0[q] = ntload4(po + q*512);
        bu1[q] = ntload4(po + q*512 + 4);
    }

#pragma unroll
    for (int it = 0; it < 8; ++it) {
        const int sl = it & 1;
        f32x4 i0 = bi0[sl], i1 = bi1[sl], u0 = bu0[sl], u1 = bu1[sl];
        if (it + 2 < 8) {
            bi0[sl] = ntload4(pi + (it+2)*512);
            bi1[sl] = ntload4(pi + (it+2)*512 + 4);
            bu0[sl] = ntload4(po + (it+2)*512);
            bu1[sl] = ntload4(po + (it+2)*512 + 4);
        }
        float ein = i0.x*wi0 + i0.y*wi1 + i0.z*wi2 + i0.w*wi3
                  + i1.x*wi4 + i1.y*wi5 + i1.z*wi6 + i1.w*wi7;
        float eut = u0.x*wo0 + u0.y*wo1 + u0.z*wo2 + u0.w*wo3
                  + u1.x*wo4 + u1.y*wo5 + u1.z*wo6 + u1.w*wo7;
        float bs = eo[it] + en;
        float si = bs + ein;  si = si > 0.f ? si : SLOPE*si;
        float so = bs + eut;  so = so > 0.f ? so : SLOPE*so;
        float wgi = ((amA >> it) & 1u) ? __expf(si) : 0.f;
        float wgo = ((amB >> it) & 1u) ? __expf(so) : 0.f;
        li += wgi; lo += wgo;
        ai[0] += wgi*i0.x; ai[1] += wgi*i0.y; ai[2] += wgi*i0.z; ai[3] += wgi*i0.w;
        ai[4] += wgi*i1.x; ai[5] += wgi*i1.y; ai[6] += wgi*i1.z; ai[7] += wgi*i1.w;
        sao[0] += u0.x; sao[1] += u0.y; sao[2] += u0.z; sao[3] += u0.w;
        sao[4] += u1.x; sao[5] += u1.y; sao[6] += u1.z; sao[7] += u1.w;
        // feat_opes row: wave-uniform cached broadcast (L1/L2-hot, 1 MB table)
        const float4* fp = (const float4*)(fo + it*INO);
        float4 f0 = fp[0], f1 = fp[1], f2 = fp[2], f3 = fp[3];
        aoi[0]  += wgi*f0.x; aoi[1]  += wgi*f0.y; aoi[2]  += wgi*f0.z; aoi[3]  += wgi*f0.w;
        aoi[4]  += wgi*f1.x; aoi[5]  += wgi*f1.y; aoi[6]  += wgi*f1.z; aoi[7]  += wgi*f1.w;
        aoi[8]  += wgi*f2.x; aoi[9]  += wgi*f2.y; aoi[10] += wgi*f2.z; aoi[11] += wgi*f2.w;
        aoi[12] += wgi*f3.x; aoi[13] += wgi*f3.y; aoi[14] += wgi*f3.z; aoi[15] += wgi*f3.w;
        aoo[0]  += wgo*f0.x; aoo[1]  += wgo*f0.y; aoo[2]  += wgo*f0.z; aoo[3]  += wgo*f0.w;
        aoo[4]  += wgo*f1.x; aoo[5]  += wgo*f1.y; aoo[6]  += wgo*f1.z; aoo[7]  += wgo*f1.w;
        aoo[8]  += wgo*f2.x; aoo[9]  += wgo*f2.y; aoo[10] += wgo*f2.z; aoo[11] += wgo*f2.w;
        aoo[12] += wgo*f3.x; aoo[13] += wgo*f3.y; aoo[14] += wgo*f3.z; aoo[15] += wgo*f3.w;
    }

    // pack full 50-field state vector (r0 layout)
    float v[50];
    v[0] = li;
#pragma unroll
    for (int k = 0; k < 8; ++k)  v[1+k]  = ai[k];
#pragma unroll
    for (int j = 0; j < 16; ++j) v[9+j]  = aoi[j];
    v[25] = lo;
#pragma unroll
    for (int j = 0; j < 16; ++j) v[26+j] = aoo[j];
#pragma unroll
    for (int k = 0; k < 8; ++k)  v[42+k] = sao[k];

    // intra-block additive reduction (waves 1..3 -> wave 0)
    if (y > 0) {
#pragma unroll
        for (int q = 0; q < 50; ++q) smem[(y-1)*3200 + q*64 + l] = v[q];
    }
    __syncthreads();
    if (y == 0) {
#pragma unroll
        for (int q = 0; q < 50; ++q)
            v[q] += smem[q*64 + l] + smem[3200 + q*64 + l] + smem[6400 + q*64 + l];
        // write-once partials -> non-temporal coalesced stores (256B runs)
        float* pp = ws + WS_PART + (size_t)bid*NPQ;
#pragma unroll
        for (int q = 0; q < 50; ++q)
            ntstore(pp + q*64 + l, v[q]);
    }
}

// ---------------- kernel B: fused 32-way reduce + epilogue (50-field layout) ----------------
__global__ __launch_bounds__(256) void k_redfin(
        const float* __restrict__ W_ope,
        const float* __restrict__ W_arc_in,
        const float* __restrict__ W_arc_out,
        const float* __restrict__ ws,
        float* __restrict__ out) {
    int tid = threadIdx.x;
    int bid = blockIdx.x;           // [0,32) = (br, b)
    int b  = bid & (B_ - 1);
    int br = bid >> 4;

    __shared__ float sW[1024];      // [0..511]=W_ope, [512..767]=W_arc_in, [768..1023]=W_arc_out
    __shared__ float red2[NPQ];     // reduced 50x64 partials for this (br,b)
    __shared__ float cinv[64][3];   // per-column inv_i, inv_o, akk

    for (int i = tid; i < 512; i += 256) sW[i] = W_ope[i];
    if (tid < 256) { sW[512 + tid] = W_arc_in[tid]; sW[768 + tid] = W_arc_out[tid]; }

    // 32-way reduction over the group's sg-blocks (dense contiguous runs)
    const float* part = ws + WS_PART;
    int pbase = br*512 + b*32;           // k_main bid of sg=0
    for (int ot = tid; ot < NPQ; ot += 256) {
        float s = 0.f;
#pragma unroll
        for (int sg = 0; sg < NSG; ++sg)
            s += part[(size_t)(pbase + sg)*NPQ + ot];
        red2[ot] = s;
    }
    __syncthreads();

    // per-column scalars
    if (tid < 64) {
        int m = tid;
        float lji = red2[m];             // field 0  = l_in
        float ljo = red2[25*64 + m];     // field 25 = l_out
        float en  = ws[WS_ENODE + (br*B_ + b)*M_ + m];
        float ekk = 2.f*en; ekk = ekk > 0.f ? ekk : SLOPE*ekk;
        float wkk = __expf(ekk);
        float inv_i = 1.f/(lji + wkk);
        float inv_o = 1.f/(ljo + wkk);
        cinv[m][0] = inv_i;
        cinv[m][1] = inv_o;
        cinv[m][2] = wkk*inv_i + wkk*inv_o;
    }
    __syncthreads();

    // epilogue: 64 columns x 32 outputs; thread -> (m, 8 consecutive c's)
    int m  = tid >> 2;
    int cq = tid & 3;
    int col = (br*B_ + b)*M_ + m;
    float inv_i = cinv[m][0], inv_o = cinv[m][1], akk = cinv[m][2];

    float vai[8], vsao[8], vaoi[16], vaoo[16];
#pragma unroll
    for (int q = 0; q < 8; ++q) {
        vai[q]  = red2[(1+q)*64  + m];
        vsao[q] = red2[(42+q)*64 + m];
    }
#pragma unroll
    for (int q = 0; q < 16; ++q) {
        vaoi[q] = red2[(9+q)*64  + m];
        vaoo[q] = red2[(26+q)*64 + m];
    }

    const float* pn = ws + WS_PNODE + (size_t)col*C_;
    float* op = out + (size_t)col*C_;
#pragma unroll
    for (int k = 0; k < 8; ++k) {
        int c = cq*8 + k;
        float s_ai = 0.f, s_oi = 0.f, s_ao = 0.f, s_oo = 0.f;
#pragma unroll
        for (int q = 0; q < 8; ++q) {
            s_ai += vai[q] *sW[512 + q*C_ + c];
            s_ao += vsao[q]*sW[768 + q*C_ + c];
        }
#pragma unroll
        for (int q = 0; q < 16; ++q) {
            float w = sW[q*C_ + c];
            s_oi += vaoi[q]*w;
            s_oo += vaoo[q]*w;
        }
        float x = (s_ai + s_oi)*inv_i + s_ao + s_oo*inv_o + pn[c]*akk;
        op[c] = 1.f/(1.f + __expf(-x));
    }
}

extern "C" void kernel_launch(void* const* d_in, const int* in_sizes, int n_in,
                              void* d_out, int out_size, void* d_ws, size_t ws_size,
                              hipStream_t stream) {
    const float* adj0 = (const float*)d_in[0];
    const float* adj1 = (const float*)d_in[1];
    const float* adj2 = (const float*)d_in[2];
    const float* adj3 = (const float*)d_in[3];
    // d_in[4] = batch_idxes (unused by the reference)
    const float* feat_opes       = (const float*)d_in[5];
    const float* feat_mas        = (const float*)d_in[6];
    const float* feat_buf        = (const float*)d_in[7];
    const float* feat_arc_ma_in  = (const float*)d_in[8];
    const float* feat_arc_buf_in = (const float*)d_in[9];
    const float* feat_arc_ma_out = (const float*)d_in[10];
    const float* feat_arc_buf_out= (const float*)d_in[11];
    const float* W_ope    = (const float*)d_in[12];
    const float* W_mas    = (const float*)d_in[13];
    const float* W_buf    = (const float*)d_in[14];
    const float* W_arc_in = (const float*)d_in[15];
    const float* W_arc_out= (const float*)d_in[16];
    const float* attn_ope = (const float*)d_in[17];
    const float* attn_mas = (const float*)d_in[18];
    const float* attn_arc = (const float*)d_in[19];

    float* ws  = (float*)d_ws;
    float* out = (float*)d_out;

    if (ws_size < (size_t)(WS_PART + GRID*NPQ)*sizeof(float)) return;

    // 64 e_ope + 8 p_node + 1 w_arc + 4 mask-pack blocks
    k_pre<<<77, 256, 0, stream>>>(adj0, adj1, adj2, adj3,
                                  feat_opes, feat_mas, feat_buf,
                                  W_ope, W_mas, W_buf, W_arc_in, W_arc_out,
                                  attn_ope, attn_mas, attn_arc, ws);

    k_main<<<GRID, 256, 0, stream>>>(feat_opes,
                                     feat_arc_ma_in, feat_arc_buf_in,
                                     feat_arc_ma_out, feat_arc_buf_out, ws);

    k_redfin<<<2*B_, 256, 0, stream>>>(W_ope, W_arc_in, W_arc_out, ws, out);
}

// Round 10
// 200.511 us; speedup vs baseline: 1.1278x; 1.1278x over previous
//
#include <hip/hip_runtime.h>
#include <math.h>

#define B_   16
#define O_   1024
#define M_   64
#define C_   32
#define INO  16
#define INA  8
#define SLOPE 0.2f

// per-block partials: 50 fields x 64 lanes
//   fields 0..24  = lo half (m = l>>1,    parity p = l&1)
//   fields 25..49 = hi half (m = 32+(l>>1), parity p)
//   within each 25: [0]=lsum(p0:l_in,p1:l_out) [1..4]=ai [5..12]=aoi
//                   [13..20]=aoo [21..24]=sao
#define NPQ   3200
#define NSG   16             // o groups of 64 rows
#define GRID  (2*B_*NSG)     // 512 blocks

// workspace layout (float offsets)
#define WS_EOPE   0
#define WS_ENODE  (WS_EOPE + B_*O_)              // 16384
#define WS_PNODE  (WS_ENODE + 2*B_*M_)           // 18432
#define WS_WARC   (WS_PNODE + 2*B_*M_*C_)        // 83968
#define WS_MASK   (WS_WARC + 16)                 // 83984 (8192 floats packed adj bits)
#define WS_PART   (WS_MASK + 8192)               // 92176 (GRID*NPQ floats = 6.5 MB)

typedef float f32x4 __attribute__((ext_vector_type(4)));

__device__ inline float rfl(float x) {
    return __int_as_float(__builtin_amdgcn_readfirstlane(__float_as_int(x)));
}

// NT load: r6 proved this bypasses the 2.7 TB/s MALL-mixed path (-> 3.5 TB/s).
// r9's lane=m attempt at full-row reads was stride-32B per instruction (bug);
// this round uses DENSE instructions covering the full row.
__device__ __forceinline__ f32x4 ntload4(const float* p) {
    return __builtin_nontemporal_load((const f32x4*)p);
}
__device__ __forceinline__ void ntstore(float* p, float v) {
    __builtin_nontemporal_store(v, p);
}

// ---------------- kernel 0: precompute (r8 version, unchanged) ----------------
__global__ void k_pre(const float* __restrict__ adj0, const float* __restrict__ adj1,
                      const float* __restrict__ adj2, const float* __restrict__ adj3,
                      const float* __restrict__ feat_opes,
                      const float* __restrict__ feat_mas,
                      const float* __restrict__ feat_buf,
                      const float* __restrict__ W_ope,
                      const float* __restrict__ W_mas,
                      const float* __restrict__ W_buf,
                      const float* __restrict__ W_arc_in,
                      const float* __restrict__ W_arc_out,
                      const float* __restrict__ attn_ope,
                      const float* __restrict__ attn_mas,
                      const float* __restrict__ attn_arc,
                      float* __restrict__ ws) {
    int tid = threadIdx.x;
    int bid = blockIdx.x;
    if (bid < 64) {
        __shared__ float wo[INO];
        if (tid < INO) {
            float s = 0.f;
            for (int c = 0; c < C_; ++c) s += W_ope[tid*C_ + c]*attn_ope[c];
            wo[tid] = s;
        }
        __syncthreads();
        int idx = bid*256 + tid;                 // [0, 16384)
        const float* f = feat_opes + idx*INO;
        float s = 0.f;
#pragma unroll
        for (int j = 0; j < INO; ++j) s += f[j]*wo[j];
        ws[WS_EOPE + idx] = s;
    } else if (bid < 72) {
        int idx = (bid - 64)*256 + tid;          // [0, 2048)
        int br  = idx >> 10;
        int rem = idx & 1023;
        const float* f = (br == 0 ? feat_mas : feat_buf) + rem*INA;
        const float* W = (br == 0 ? W_mas : W_buf);
        float f8[INA];
#pragma unroll
        for (int k = 0; k < INA; ++k) f8[k] = f[k];
        float e = 0.f;
        float* pn = ws + WS_PNODE + idx*C_;
        for (int c = 0; c < C_; ++c) {
            float s = 0.f;
#pragma unroll
            for (int k = 0; k < INA; ++k) s += f8[k]*W[k*C_ + c];
            pn[c] = s;
            e += s*attn_mas[c];
        }
        ws[WS_ENODE + idx] = e;
    } else if (bid == 72) {
        if (tid < 16) {
            const float* W = (tid < 8) ? W_arc_in : W_arc_out;
            int k = tid & 7;
            float s = 0.f;
            for (int c = 0; c < C_; ++c) s += W[k*C_ + c]*attn_arc[c];
            ws[WS_WARC + tid] = s;
        }
    } else {
        // bid 73..76: coalesced mask packing, one block per adjacency matrix.
        int q  = bid - 73;                  // 0:adj0(in,br0) 1:adj1(out,br0) 2:adj2 3:adj3
        const float* A = (q == 0) ? adj0 : (q == 1) ? adj1 : (q == 2) ? adj2 : adj3;
        int br = q >> 1;
        int l  = tid & 63;
        int y  = tid >> 6;
        int mq = l & 15;
        int oo = l >> 4;
        unsigned* mp = (unsigned*)(ws + WS_MASK);
        for (int t = 0; t < 8; ++t) {
            int j4 = y*8 + t;               // o-group [j4*32, j4*32+32)
            unsigned mk0 = 0u, mk1 = 0u, mk2 = 0u, mk3 = 0u;
#pragma unroll
            for (int g2 = 0; g2 < 8; ++g2) {
                int o = j4*32 + g2*4 + oo;
                float4 v = *(const float4*)(A + o*M_ + mq*4);
                unsigned bit = 1u << (g2*4 + oo);
                if (v.x == 1.0f) mk0 |= bit;
                if (v.y == 1.0f) mk1 |= bit;
                if (v.z == 1.0f) mk2 |= bit;
                if (v.w == 1.0f) mk3 |= bit;
            }
            mk0 |= (unsigned)__shfl_xor((int)mk0, 16); mk0 |= (unsigned)__shfl_xor((int)mk0, 32);
            mk1 |= (unsigned)__shfl_xor((int)mk1, 16); mk1 |= (unsigned)__shfl_xor((int)mk1, 32);
            mk2 |= (unsigned)__shfl_xor((int)mk2, 16); mk2 |= (unsigned)__shfl_xor((int)mk2, 32);
            mk3 |= (unsigned)__shfl_xor((int)mk3, 16); mk3 |= (unsigned)__shfl_xor((int)mk3, 32);
            if (oo == 0) {
                int base = (br*M_ + mq*4)*64 + (q & 1)*32 + j4;
                mp[base]        = mk0;
                mp[base + 64]   = mk1;
                mp[base + 128]  = mk2;
                mp[base + 192]  = mk3;
            }
        }
    }
}

// ---------------- kernel A: full-row waves with DENSE instructions ----------------
// Each wave reads the COMPLETE 2KB row o: lane l -> floats [l*4, l*4+4) (first
// KB = m 0..31 parity-split) and [256+l*4, ...) (second KB = m 32..63). Two
// back-to-back dense 1KB dwordx4 per tensor per row: every DRAM page touched
// once, in full, by one wave (the clean test of the r8 half-page theory; r9's
// version was stride-32B per instruction -- wrong). Each lane accumulates both
// half-columns' parity state (50 fields). feat pass folded (VALU is 12% idle).
__global__ __launch_bounds__(256) void k_main(
        const float* __restrict__ feat_opes,
        const float* __restrict__ fin_ma,  const float* __restrict__ fin_buf,
        const float* __restrict__ fout_ma, const float* __restrict__ fout_buf,
        float* __restrict__ ws) {
    int tid = threadIdx.x;
    int l   = tid & 63;
    int p   = l & 1;                                  // parity (k-half)
    int ml  = l >> 1;                                 // lo m; hi m = 32+ml
    int y   = __builtin_amdgcn_readfirstlane(tid >> 6);

    int bid = blockIdx.x;                 // [0, 512)
    int sg  = bid & (NSG - 1);            // 64-row group
    int b   = (bid >> 4) & (B_ - 1);
    int br  = bid >> 8;

    const float* fin  = br ? fin_buf  : fin_ma;
    const float* fout = br ? fout_buf : fout_ma;

    __shared__ float smem[9600];          // 3 waves x 50 x 64

    float en_lo = ws[WS_ENODE + (br*B_ + b)*M_ + ml];
    float en_hi = ws[WS_ENODE + (br*B_ + b)*M_ + 32 + ml];

    // per-parity 4-element weight slices
    const float* wv = ws + WS_WARC + 4*p;
    float wiA = wv[0], wiB = wv[1], wiC = wv[2], wiD = wv[3];
    float woA = wv[8], woB = wv[9], woC = wv[10], woD = wv[11];

    const unsigned* mbase = (const unsigned*)(ws + WS_MASK);
    const unsigned* mpl = mbase + (br*M_ + ml)*64;
    const unsigned* mph = mbase + (br*M_ + 32 + ml)*64;

    float vlo[25], vhi[25];
#pragma unroll
    for (int q = 0; q < 25; ++q) { vlo[q] = 0.f; vhi[q] = 0.f; }

#pragma unroll
    for (int c = 0; c < 2; ++c) {
        int o0 = sg*64 + c*32 + y*8;      // this wave: o in [o0, o0+8)
        const float* pi = fin  + (size_t)(b*O_ + o0)*512 + l*4;
        const float* po = fout + (size_t)(b*O_ + o0)*512 + l*4;
        const float* fo = feat_opes + (size_t)(b*O_ + o0)*INO + p*8;

        const float* e_ope = ws + WS_EOPE + b*O_ + o0;
        float eo[8];
#pragma unroll
        for (int i = 0; i < 8; ++i) eo[i] = rfl(e_ope[i]);

        int j4 = sg*2 + c;
        unsigned amAl = (mpl[j4]      >> (y*8)) & 0xffu;
        unsigned amBl = (mpl[32 + j4] >> (y*8)) & 0xffu;
        unsigned amAh = (mph[j4]      >> (y*8)) & 0xffu;
        unsigned amBh = (mph[32 + j4] >> (y*8)) & 0xffu;

        // depth-2 rotating NT pipeline over full rows (4 dense KB-loads/row)
        f32x4 bi0[2], bi1[2], bu0[2], bu1[2];
#pragma unroll
        for (int q = 0; q < 2; ++q) {
            bi0[q] = ntload4(pi + q*512);
            bi1[q] = ntload4(pi + q*512 + 256);
            bu0[q] = ntload4(po + q*512);
            bu1[q] = ntload4(po + q*512 + 256);
        }

#pragma unroll
        for (int it = 0; it < 8; ++it) {
            const int sl = it & 1;
            f32x4 i0 = bi0[sl], i1 = bi1[sl], u0 = bu0[sl], u1 = bu1[sl];
            if (it + 2 < 8) {
                bi0[sl] = ntload4(pi + (it+2)*512);
                bi1[sl] = ntload4(pi + (it+2)*512 + 256);
                bu0[sl] = ntload4(po + (it+2)*512);
                bu1[sl] = ntload4(po + (it+2)*512 + 256);
            }
            // parity-partial dots, completed across the lane pair
            float eil = i0.x*wiA + i0.y*wiB + i0.z*wiC + i0.w*wiD;
            float eih = i1.x*wiA + i1.y*wiB + i1.z*wiC + i1.w*wiD;
            float eul = u0.x*woA + u0.y*woB + u0.z*woC + u0.w*woD;
            float euh = u1.x*woA + u1.y*woB + u1.z*woC + u1.w*woD;
            eil += __shfl_xor(eil, 1);
            eih += __shfl_xor(eih, 1);
            eul += __shfl_xor(eul, 1);
            euh += __shfl_xor(euh, 1);

            float bl = eo[it] + en_lo;
            float bh = eo[it] + en_hi;
            float sil = bl + eil;  sil = sil > 0.f ? sil : SLOPE*sil;
            float sol = bl + eul;  sol = sol > 0.f ? sol : SLOPE*sol;
            float sih = bh + eih;  sih = sih > 0.f ? sih : SLOPE*sih;
            float soh = bh + euh;  soh = soh > 0.f ? soh : SLOPE*soh;
            float wgil = ((amAl >> it) & 1u) ? __expf(sil) : 0.f;
            float wgol = ((amBl >> it) & 1u) ? __expf(sol) : 0.f;
            float wgih = ((amAh >> it) & 1u) ? __expf(sih) : 0.f;
            float wgoh = ((amBh >> it) & 1u) ? __expf(soh) : 0.f;

            vlo[0] += p ? wgol : wgil;
            vhi[0] += p ? wgoh : wgih;
            vlo[1] += wgil*i0.x; vlo[2] += wgil*i0.y; vlo[3] += wgil*i0.z; vlo[4] += wgil*i0.w;
            vhi[1] += wgih*i1.x; vhi[2] += wgih*i1.y; vhi[3] += wgih*i1.z; vhi[4] += wgih*i1.w;
            vlo[21] += u0.x; vlo[22] += u0.y; vlo[23] += u0.z; vlo[24] += u0.w;
            vhi[21] += u1.x; vhi[22] += u1.y; vhi[23] += u1.z; vhi[24] += u1.w;

            // feat_opes row: wave-uniform cached broadcast (1 MB table, L2-hot)
            float4 f0 = *(const float4*)(fo + it*INO);
            float4 f1 = *(const float4*)(fo + it*INO + 4);
            vlo[5]  += wgil*f0.x; vlo[6]  += wgil*f0.y; vlo[7]  += wgil*f0.z; vlo[8]  += wgil*f0.w;
            vlo[9]  += wgil*f1.x; vlo[10] += wgil*f1.y; vlo[11] += wgil*f1.z; vlo[12] += wgil*f1.w;
            vlo[13] += wgol*f0.x; vlo[14] += wgol*f0.y; vlo[15] += wgol*f0.z; vlo[16] += wgol*f0.w;
            vlo[17] += wgol*f1.x; vlo[18] += wgol*f1.y; vlo[19] += wgol*f1.z; vlo[20] += wgol*f1.w;
            vhi[5]  += wgih*f0.x; vhi[6]  += wgih*f0.y; vhi[7]  += wgih*f0.z; vhi[8]  += wgih*f0.w;
            vhi[9]  += wgih*f1.x; vhi[10] += wgih*f1.y; vhi[11] += wgih*f1.z; vhi[12] += wgih*f1.w;
            vhi[13] += wgoh*f0.x; vhi[14] += wgoh*f0.y; vhi[15] += wgoh*f0.z; vhi[16] += wgoh*f0.w;
            vhi[17] += wgoh*f1.x; vhi[18] += wgoh*f1.y; vhi[19] += wgoh*f1.z; vhi[20] += wgoh*f1.w;
        }
    }

    // intra-block additive reduction (waves 1..3 -> wave 0)
    if (y > 0) {
#pragma unroll
        for (int q = 0; q < 25; ++q) {
            smem[(y-1)*3200 + q*64 + l]        = vlo[q];
            smem[(y-1)*3200 + (25+q)*64 + l]   = vhi[q];
        }
    }
    __syncthreads();
    if (y == 0) {
#pragma unroll
        for (int q = 0; q < 25; ++q) {
            vlo[q] += smem[q*64 + l]      + smem[3200 + q*64 + l]      + smem[6400 + q*64 + l];
            vhi[q] += smem[(25+q)*64 + l] + smem[3200 + (25+q)*64 + l] + smem[6400 + (25+q)*64 + l];
        }
        float* pp = ws + WS_PART + (size_t)bid*NPQ;
#pragma unroll
        for (int q = 0; q < 25; ++q) {
            ntstore(pp + q*64 + l,       vlo[q]);
            ntstore(pp + (25+q)*64 + l,  vhi[q]);
        }
    }
}

// ---------------- kernel B: fused 16-way reduce + epilogue (r8 structure) ----------------
__global__ __launch_bounds__(256) void k_redfin(
        const float* __restrict__ W_ope,
        const float* __restrict__ W_arc_in,
        const float* __restrict__ W_arc_out,
        const float* __restrict__ ws,
        float* __restrict__ out) {
    int tid = threadIdx.x;
    int bid = blockIdx.x;           // [0,64)
    int hf = bid & 1;
    int b  = (bid >> 1) & (B_ - 1);
    int br = bid >> 5;

    __shared__ float sW[1024];      // [0..511]=W_ope, [512..767]=W_arc_in, [768..1023]=W_arc_out
    __shared__ float red2[25*64];   // reduced partials for this (br,b,half)
    __shared__ float cinv[32][3];   // per-column inv_i, inv_o, akk

    for (int i = tid; i < 512; i += 256) sW[i] = W_ope[i];
    if (tid < 256) { sW[512 + tid] = W_arc_in[tid]; sW[768 + tid] = W_arc_out[tid]; }

    // 16-way reduction over the group's sg-blocks (dense 256B runs)
    const float* part = ws + WS_PART;
    int pbase = (br*B_ + b)*NSG;         // k_main bid of sg=0
    int qoff  = hf*25*64;
    for (int ot = tid; ot < 25*64; ot += 256) {
        float s = 0.f;
#pragma unroll
        for (int sg = 0; sg < NSG; ++sg)
            s += part[(size_t)(pbase + sg)*NPQ + qoff + ot];
        red2[ot] = s;
    }
    __syncthreads();

    // per-column scalars
    if (tid < 32) {
        int j = tid;
        int col = (br*B_ + b)*M_ + hf*32 + j;
        float li = red2[2*j];            // field 0 @ even lane = l_in
        float lo = red2[2*j + 1];        // field 0 @ odd lane  = l_out
        float en  = ws[WS_ENODE + col];
        float ekk = 2.f*en; ekk = ekk > 0.f ? ekk : SLOPE*ekk;
        float wkk = __expf(ekk);
        float inv_i = 1.f/(li + wkk);
        float inv_o = 1.f/(lo + wkk);
        cinv[j][0] = inv_i;
        cinv[j][1] = inv_o;
        cinv[j][2] = wkk*inv_i + wkk*inv_o;
    }
    __syncthreads();

    // epilogue: 32 columns x 32 outputs; thread -> (j, 4 c's)
    int j  = tid >> 3;
    int c0 = tid & 7;
    int col = (br*B_ + b)*M_ + hf*32 + j;
    int l0 = 2*j, l1 = 2*j + 1;

    float vai[8], vsao[8], vaoi[16], vaoo[16];
#pragma unroll
    for (int k = 0; k < 4; ++k) {
        vai[k]    = red2[(1+k)*64  + l0];
        vai[4+k]  = red2[(1+k)*64  + l1];
        vsao[k]   = red2[(21+k)*64 + l0];
        vsao[4+k] = red2[(21+k)*64 + l1];
    }
#pragma unroll
    for (int k = 0; k < 8; ++k) {
        vaoi[k]   = red2[(5+k)*64  + l0];
        vaoi[8+k] = red2[(5+k)*64  + l1];
        vaoo[k]   = red2[(13+k)*64 + l0];
        vaoo[8+k] = red2[(13+k)*64 + l1];
    }

    float inv_i = cinv[j][0], inv_o = cinv[j][1], akk = cinv[j][2];
    const float* pn = ws + WS_PNODE + (size_t)col*C_;
    float* op = out + (size_t)col*C_;

#pragma unroll
    for (int k = 0; k < 4; ++k) {
        int c = c0 + 8*k;
        float s_ai = 0.f, s_oi = 0.f, s_ao = 0.f, s_oo = 0.f;
#pragma unroll
        for (int q = 0; q < 8; ++q) {
            s_ai += vai[q] *sW[512 + q*C_ + c];
            s_ao += vsao[q]*sW[768 + q*C_ + c];
        }
#pragma unroll
        for (int q = 0; q < 16; ++q) {
            float wv = sW[q*C_ + c];
            s_oi += vaoi[q]*wv;
            s_oo += vaoo[q]*wv;
        }
        float x = (s_ai + s_oi)*inv_i + s_ao + s_oo*inv_o + pn[c]*akk;
        op[c] = 1.f/(1.f + __expf(-x));
    }
}

extern "C" void kernel_launch(void* const* d_in, const int* in_sizes, int n_in,
                              void* d_out, int out_size, void* d_ws, size_t ws_size,
                              hipStream_t stream) {
    const float* adj0 = (const float*)d_in[0];
    const float* adj1 = (const float*)d_in[1];
    const float* adj2 = (const float*)d_in[2];
    const float* adj3 = (const float*)d_in[3];
    // d_in[4] = batch_idxes (unused by the reference)
    const float* feat_opes       = (const float*)d_in[5];
    const float* feat_mas        = (const float*)d_in[6];
    const float* feat_buf        = (const float*)d_in[7];
    const float* feat_arc_ma_in  = (const float*)d_in[8];
    const float* feat_arc_buf_in = (const float*)d_in[9];
    const float* feat_arc_ma_out = (const float*)d_in[10];
    const float* feat_arc_buf_out= (const float*)d_in[11];
    const float* W_ope    = (const float*)d_in[12];
    const float* W_mas    = (const float*)d_in[13];
    const float* W_buf    = (const float*)d_in[14];
    const float* W_arc_in = (const float*)d_in[15];
    const float* W_arc_out= (const float*)d_in[16];
    const float* attn_ope = (const float*)d_in[17];
    const float* attn_mas = (const float*)d_in[18];
    const float* attn_arc = (const float*)d_in[19];

    float* ws  = (float*)d_ws;
    float* out = (float*)d_out;

    if (ws_size < (size_t)(WS_PART + GRID*NPQ)*sizeof(float)) return;

    // 64 e_ope + 8 p_node + 1 w_arc + 4 mask-pack blocks
    k_pre<<<77, 256, 0, stream>>>(adj0, adj1, adj2, adj3,
                                  feat_opes, feat_mas, feat_buf,
                                  W_ope, W_mas, W_buf, W_arc_in, W_arc_out,
                                  attn_ope, attn_mas, attn_arc, ws);

    k_main<<<GRID, 256, 0, stream>>>(feat_opes,
                                     feat_arc_ma_in, feat_arc_buf_in,
                                     feat_arc_ma_out, feat_arc_buf_out, ws);

    k_redfin<<<2*B_*2, 256, 0, stream>>>(W_ope, W_arc_in, W_arc_out, ws, out);
}